// Round 4
// baseline (339.147 us; speedup 1.0000x reference)
//
#include <hip/hip_runtime.h>
#include <math.h>

#define BB 64
#define LL 200
#define DD 128
#define MM 50
#define NQ 10000
#define NPOS (BB * LL)   // 12800
#define LC 20            // scan chunk length
#define NC 10            // number of chunks (LC*NC == LL)

__device__ __forceinline__ float dot4(float4 a, float4 b, float c) {
    return fmaf(a.x, b.x, fmaf(a.y, b.y, fmaf(a.z, b.z, fmaf(a.w, b.w, c))));
}

// ---------------------------------------------------------------------------
// Kernel 1a: w = softmax(k @ Mk^T). 64 positions/block, 256 thr.
// lanes = positions; Mk rows via wave-uniform s_load; k from LDS registers.
// ---------------------------------------------------------------------------
__global__ __launch_bounds__(256) void k_w(
    const int* __restrict__ q, const float* __restrict__ k_emb,
    const float* __restrict__ Mk, float* __restrict__ w_ws)
{
    __shared__ float k_lds[64][132];
    __shared__ float lg[64][52];
    __shared__ float winv[64];

    const int tid = threadIdx.x;
    const int p0  = blockIdx.x * 64;

    #pragma unroll
    for (int rep = 0; rep < 8; ++rep) {
        int idx = rep * 256 + tid;
        int pos = idx >> 5, c4 = idx & 31;
        int qi  = q[p0 + pos];
        *(float4*)&k_lds[pos][c4 * 4] =
            *(const float4*)(k_emb + (size_t)qi * DD + c4 * 4);
    }
    __syncthreads();

    const int w    = __builtin_amdgcn_readfirstlane(tid >> 6);
    const int pos  = tid & 63;
    const int m0   = w * 13;
    const int mcnt = (w == 3) ? 11 : 13;

    float acc[13];
    #pragma unroll
    for (int s = 0; s < 13; ++s) acc[s] = 0.f;

    for (int j4 = 0; j4 < 32; ++j4) {
        float4 k4 = *(float4*)&k_lds[pos][j4 * 4];
        #pragma unroll
        for (int s = 0; s < 13; ++s)
            if (s < mcnt)
                acc[s] = dot4(k4, *(const float4*)(Mk + (size_t)(m0 + s) * DD + j4 * 4), acc[s]);
    }
    #pragma unroll
    for (int s = 0; s < 13; ++s)
        if (s < mcnt) lg[pos][m0 + s] = acc[s];
    __syncthreads();

    if (tid < 64) {
        float mx = -INFINITY;
        for (int m = 0; m < MM; ++m) mx = fmaxf(mx, lg[tid][m]);
        float sum = 0.f;
        for (int m = 0; m < MM; ++m) {
            float e = expf(lg[tid][m] - mx);
            lg[tid][m] = e;
            sum += e;
        }
        winv[tid] = 1.f / sum;
    }
    __syncthreads();

    for (int idx = tid; idx < 64 * MM; idx += 256) {
        int pp = idx / MM, m = idx - pp * MM;
        w_ws[(size_t)(p0 + pp) * MM + m] = lg[pp][m] * winv[pp];
    }
}

// ---------------------------------------------------------------------------
// Kernel 1b: e = sigmoid(v@e_W^T+e_b), a = tanh(v@a_W^T+a_b).
// 128 thr, 400 blocks = (200 pos-groups) x (2 i-halves). lanes = positions;
// weights via wave-uniform s_load; LDS transpose buffer for coalesced stores.
// ---------------------------------------------------------------------------
__global__ __launch_bounds__(128) void k_ea(
    const int* __restrict__ q, const int* __restrict__ r,
    const float* __restrict__ v_emb,
    const float* __restrict__ e_W, const float* __restrict__ e_b,
    const float* __restrict__ a_W, const float* __restrict__ a_b,
    float* __restrict__ e_ws, float* __restrict__ a_ws)
{
    __shared__ float v_lds[64][132];
    __shared__ float buf_e[2][64][36];
    __shared__ float buf_a[2][64][36];

    const int tid = threadIdx.x;
    const int pg  = blockIdx.x >> 1, h = blockIdx.x & 1;
    const int p0  = pg * 64;

    #pragma unroll
    for (int rep = 0; rep < 16; ++rep) {
        int idx = rep * 128 + tid;
        int pos = idx >> 5, c4 = idx & 31;
        int gp  = p0 + pos;
        int xi  = q[gp] + NQ * r[gp];
        *(float4*)&v_lds[pos][c4 * 4] =
            *(const float4*)(v_emb + (size_t)xi * DD + c4 * 4);
    }
    __syncthreads();

    const int w    = __builtin_amdgcn_readfirstlane(tid >> 6);
    const int lane = tid & 63;
    const int i0   = h * 64 + w * 32;

    float ae[32], aa[32];
    #pragma unroll
    for (int ii = 0; ii < 32; ++ii) { ae[ii] = e_b[i0 + ii]; aa[ii] = a_b[i0 + ii]; }

    for (int j4 = 0; j4 < 32; ++j4) {
        float4 v4 = *(float4*)&v_lds[lane][j4 * 4];
        #pragma unroll
        for (int ii = 0; ii < 32; ++ii) {
            ae[ii] = dot4(v4, *(const float4*)(e_W + (size_t)(i0 + ii) * DD + j4 * 4), ae[ii]);
            aa[ii] = dot4(v4, *(const float4*)(a_W + (size_t)(i0 + ii) * DD + j4 * 4), aa[ii]);
        }
    }

    #pragma unroll
    for (int ii = 0; ii < 32; ++ii) {
        buf_e[w][lane][ii] = 1.f / (1.f + expf(-ae[ii]));
        buf_a[w][lane][ii] = tanhf(aa[ii]);
    }
    // wave-private buffer: same wave reads back, no __syncthreads needed
    #pragma unroll
    for (int rep = 0; rep < 8; ++rep) {
        int idx = rep * 64 + lane;
        int pp = idx >> 3, c4 = idx & 7;
        *(float4*)(e_ws + (size_t)(p0 + pp) * DD + i0 + c4 * 4) = *(float4*)&buf_e[w][pp][c4 * 4];
        *(float4*)(a_ws + (size_t)(p0 + pp) * DD + i0 + c4 * 4) = *(float4*)&buf_a[w][pp][c4 * 4];
    }
}

// ---------------------------------------------------------------------------
// Kernel 2a: per (b, chunk) affine composite S_out = A*S_in + B per (m,d).
// ---------------------------------------------------------------------------
__global__ __launch_bounds__(512) void k_scanA(
    const float* __restrict__ w_ws, const float* __restrict__ e_ws,
    const float* __restrict__ a_ws,
    float* __restrict__ A_ws, float* __restrict__ B_ws)
{
    __shared__ float w_lds[LC * MM];   // 4 KB

    const int b   = blockIdx.x / NC;
    const int c   = blockIdx.x % NC;
    const int tid = threadIdx.x;
    const int d   = tid & 127;
    const int g   = tid >> 7;
    int moff = g * 13; if (g == 3) moff = 38;
    const int mcnt = (g < 2) ? 13 : 12;

    const float* wsrc = w_ws + ((size_t)b * LL + c * LC) * MM;  // contiguous
    for (int idx = tid; idx < LC * MM; idx += 512) w_lds[idx] = wsrc[idx];
    __syncthreads();

    float A[13], Bv[13];
    #pragma unroll
    for (int mi = 0; mi < 13; ++mi) { A[mi] = 1.f; Bv[mi] = 0.f; }

    for (int ll = 0; ll < LC; ++ll) {
        const int gp = b * LL + c * LC + ll;
        const float e = e_ws[(size_t)gp * DD + d];
        const float a = a_ws[(size_t)gp * DD + d];
        const float* wl = w_lds + ll * MM + moff;
        #pragma unroll
        for (int mi = 0; mi < 13; ++mi) {
            if (mi < mcnt) {
                float w_ = wl[mi];
                float cc = fmaf(-w_, e, 1.f);
                A[mi] *= cc;
                Bv[mi] = fmaf(Bv[mi], cc, w_ * a);
            }
        }
    }

    float* Ao = A_ws + ((size_t)b * NC + c) * MM * DD + (size_t)moff * DD + d;
    float* Bo = B_ws + ((size_t)b * NC + c) * MM * DD + (size_t)moff * DD + d;
    #pragma unroll
    for (int mi = 0; mi < 13; ++mi) {
        if (mi < mcnt) { Ao[mi * DD] = A[mi]; Bo[mi * DD] = Bv[mi]; }
    }
}

// ---------------------------------------------------------------------------
// Kernel 2b: sequential composition over chunks; writes chunk ENTRY states
// in-place over A_ws. One thread per (b,m,d).
// ---------------------------------------------------------------------------
__global__ __launch_bounds__(256) void k_scanB(
    const float* __restrict__ Mv0,
    float* __restrict__ A_ws,            // in: A, out: Sentry
    const float* __restrict__ B_ws)
{
    const int g  = blockIdx.x * 256 + threadIdx.x;   // 0 .. B*M*D-1
    const int d  = g & (DD - 1);
    const int md = g >> 7;
    const int m  = md % MM;
    const int b  = md / MM;

    float S = Mv0[m * DD + d];
    const size_t base = ((size_t)b * NC * MM + m) * DD + d;
    #pragma unroll
    for (int c = 0; c < NC; ++c) {
        const size_t off = base + (size_t)c * MM * DD;
        const float Ac = A_ws[off];
        const float Bc = B_ws[off];
        A_ws[off] = S;                     // entry state of chunk c
        S = fmaf(Ac, S, Bc);
    }
}

// ---------------------------------------------------------------------------
// Kernel 2c: replay the scan per (b, chunk) from its entry state; writes all
// Mv states and read[b,l,d] = sum_m w*Mv_pre.
// ---------------------------------------------------------------------------
__global__ __launch_bounds__(512) void k_scanC(
    const float* __restrict__ Sentry,     // == A_ws after k_scanB
    const float* __restrict__ w_ws, const float* __restrict__ e_ws,
    const float* __restrict__ a_ws,
    float* __restrict__ read_ws, float* __restrict__ out_Mv)
{
    __shared__ float w_lds[LC * MM];      // 4 KB
    __shared__ float red[2][4][DD];       // 4 KB

    const int b   = blockIdx.x / NC;
    const int c   = blockIdx.x % NC;
    const int tid = threadIdx.x;
    const int d   = tid & 127;
    const int g   = tid >> 7;
    int moff = g * 13; if (g == 3) moff = 38;
    const int mcnt = (g < 2) ? 13 : 12;

    const float* wsrc = w_ws + ((size_t)b * LL + c * LC) * MM;
    for (int idx = tid; idx < LC * MM; idx += 512) w_lds[idx] = wsrc[idx];

    float S[13];
    const float* Sp = Sentry + ((size_t)b * NC + c) * MM * DD + (size_t)moff * DD + d;
    #pragma unroll
    for (int mi = 0; mi < 13; ++mi)
        if (mi < mcnt) S[mi] = Sp[mi * DD];

    float* outb = out_Mv + (size_t)b * (LL + 1) * MM * DD;
    if (c == 0) {
        #pragma unroll
        for (int mi = 0; mi < 13; ++mi)
            if (mi < mcnt) outb[(moff + mi) * DD + d] = S[mi];  // init state
    }
    __syncthreads();

    for (int ll = 0; ll < LC; ++ll) {
        const int l  = c * LC + ll;
        const int gp = b * LL + l;
        const float e = e_ws[(size_t)gp * DD + d];
        const float a = a_ws[(size_t)gp * DD + d];
        const float* wl = w_lds + ll * MM + moff;

        float racc = 0.f;
        float* o = outb + (size_t)(l + 1) * MM * DD + d;
        #pragma unroll
        for (int mi = 0; mi < 13; ++mi) {
            if (mi < mcnt) {
                float w_ = wl[mi];
                racc = fmaf(w_, S[mi], racc);                // pre-update read
                S[mi] = fmaf(w_, fmaf(-S[mi], e, a), S[mi]); // S += w*(a - S*e)
                o[(moff + mi) * DD] = S[mi];
            }
        }
        red[ll & 1][g][d] = racc;
        __syncthreads();
        if (g == 0)
            read_ws[(size_t)gp * DD + d] =
                red[ll & 1][0][d] + red[ll & 1][1][d] +
                red[ll & 1][2][d] + red[ll & 1][3][d];
    }
}

// ---------------------------------------------------------------------------
// Kernel 3: f = tanh([read,k] @ f_W^T + f_b); p = sigmoid(f . p_W + p_b).
// 64 positions/block, 256 thr; lanes = positions, f_W/p_W via s_load.
// Only p survives -> in-lane dot, cross-wave LDS reduce, no transpose.
// ---------------------------------------------------------------------------
__global__ __launch_bounds__(256) void k_fp(
    const int* __restrict__ q,
    const float* __restrict__ k_emb,
    const float* __restrict__ read_ws,
    const float* __restrict__ f_W, const float* __restrict__ f_b,
    const float* __restrict__ p_W, const float* __restrict__ p_b,
    float* __restrict__ out_p)
{
    __shared__ float rd_l[64][132];
    __shared__ float kk_l[64][132];
    __shared__ float p_red[4][64];

    const int tid = threadIdx.x;
    const int p0  = blockIdx.x * 64;

    #pragma unroll
    for (int rep = 0; rep < 8; ++rep) {
        int idx = rep * 256 + tid;
        int pos = idx >> 5, c4 = idx & 31;
        int gp  = p0 + pos;
        *(float4*)&rd_l[pos][c4 * 4] =
            *(const float4*)(read_ws + (size_t)gp * DD + c4 * 4);
        int qi = q[gp];
        *(float4*)&kk_l[pos][c4 * 4] =
            *(const float4*)(k_emb + (size_t)qi * DD + c4 * 4);
    }
    __syncthreads();

    const int w    = __builtin_amdgcn_readfirstlane(tid >> 6);
    const int lane = tid & 63;
    const int i0   = w * 32;

    float acc[32];
    #pragma unroll
    for (int ii = 0; ii < 32; ++ii) acc[ii] = f_b[i0 + ii];

    for (int j4 = 0; j4 < 32; ++j4) {
        float4 r4 = *(float4*)&rd_l[lane][j4 * 4];
        #pragma unroll
        for (int ii = 0; ii < 32; ++ii)
            acc[ii] = dot4(r4, *(const float4*)(f_W + (size_t)(i0 + ii) * (2 * DD) + j4 * 4), acc[ii]);
    }
    for (int j4 = 0; j4 < 32; ++j4) {
        float4 k4 = *(float4*)&kk_l[lane][j4 * 4];
        #pragma unroll
        for (int ii = 0; ii < 32; ++ii)
            acc[ii] = dot4(k4, *(const float4*)(f_W + (size_t)(i0 + ii) * (2 * DD) + DD + j4 * 4), acc[ii]);
    }

    float pp = 0.f;
    #pragma unroll
    for (int ii = 0; ii < 32; ++ii)
        pp = fmaf(tanhf(acc[ii]), p_W[i0 + ii], pp);
    p_red[w][lane] = pp;
    __syncthreads();

    if (tid < 64) {
        float s = p_red[0][tid] + p_red[1][tid] + p_red[2][tid] + p_red[3][tid] + p_b[0];
        out_p[p0 + tid] = 1.f / (1.f + expf(-s));
    }
}

// ---------------------------------------------------------------------------
extern "C" void kernel_launch(void* const* d_in, const int* in_sizes, int n_in,
                              void* d_out, int out_size, void* d_ws, size_t ws_size,
                              hipStream_t stream)
{
    const int*   q     = (const int*)d_in[0];
    const int*   r     = (const int*)d_in[1];
    const float* k_emb = (const float*)d_in[2];
    const float* v_emb = (const float*)d_in[3];
    const float* Mk    = (const float*)d_in[4];
    const float* Mv0   = (const float*)d_in[5];
    const float* f_W   = (const float*)d_in[6];
    const float* f_b   = (const float*)d_in[7];
    const float* p_W   = (const float*)d_in[8];
    const float* p_b   = (const float*)d_in[9];
    const float* e_W   = (const float*)d_in[10];
    const float* e_b   = (const float*)d_in[11];
    const float* a_W   = (const float*)d_in[12];
    const float* a_b   = (const float*)d_in[13];

    float* out_p  = (float*)d_out;           // [B,L]
    float* out_Mv = out_p + NPOS;            // [B,L+1,M,D]

    float* w_ws    = (float*)d_ws;                         // NPOS*MM
    float* e_ws    = w_ws + (size_t)NPOS * MM;             // NPOS*DD
    float* a_ws    = e_ws + (size_t)NPOS * DD;             // NPOS*DD
    float* read_ws = a_ws + (size_t)NPOS * DD;             // NPOS*DD
    float* A_ws    = read_ws + (size_t)NPOS * DD;          // B*NC*MM*DD
    float* B_ws    = A_ws + (size_t)BB * NC * MM * DD;     // B*NC*MM*DD

    hipLaunchKernelGGL(k_w, dim3(NPOS / 64), dim3(256), 0, stream,
                       q, k_emb, Mk, w_ws);
    hipLaunchKernelGGL(k_ea, dim3(2 * NPOS / 64), dim3(128), 0, stream,
                       q, r, v_emb, e_W, e_b, a_W, a_b, e_ws, a_ws);
    hipLaunchKernelGGL(k_scanA, dim3(BB * NC), dim3(512), 0, stream,
                       w_ws, e_ws, a_ws, A_ws, B_ws);
    hipLaunchKernelGGL(k_scanB, dim3((BB * MM * DD) / 256), dim3(256), 0, stream,
                       Mv0, A_ws, B_ws);
    hipLaunchKernelGGL(k_scanC, dim3(BB * NC), dim3(512), 0, stream,
                       A_ws, w_ws, e_ws, a_ws, read_ws, out_Mv);
    hipLaunchKernelGGL(k_fp, dim3(NPOS / 64), dim3(256), 0, stream,
                       q, k_emb, read_ws, f_W, f_b, p_W, p_b, out_p);
}

// Round 5
// 308.072 us; speedup vs baseline: 1.1009x; 1.1009x over previous
//
#include <hip/hip_runtime.h>
#include <math.h>

#define BB 64
#define LL 200
#define DD 128
#define MM 50
#define NQ 10000
#define NPOS (BB * LL)   // 12800
#define LC 20            // scan chunk length
#define NC 10            // number of chunks (LC*NC == LL)

#define PAD_KV 132       // k/v row stride in LDS
#define MKT_LD 52        // transposed-Mk row stride
#define EW_LD 133        // e_W/a_W chunk row stride (133%32=5, odd -> conflict-free lane reads)
#define FW_LD 261        // f_W chunk row stride (261%32=5)

__device__ __forceinline__ float dot4(float4 a, float4 b, float c) {
    return fmaf(a.x, b.x, fmaf(a.y, b.y, fmaf(a.z, b.z, fmaf(a.w, b.w, c))));
}

// ---------------------------------------------------------------------------
// Kernel 1: fused w/e/a. Block = 16 positions, 256 threads.
// All weight matrices staged in LDS (coalesced once), inner loops read
// weights from LDS (broadcast / odd-stride conflict-free), v/k from LDS.
// LDS: max(phaseA 35KB, phaseB 42.5KB) + lg ~3.4KB  => ~46KB, 3 blocks/CU.
// ---------------------------------------------------------------------------
__global__ __launch_bounds__(256) void k_wea(
    const int* __restrict__ q, const int* __restrict__ r,
    const float* __restrict__ k_emb, const float* __restrict__ v_emb,
    const float* __restrict__ Mk,
    const float* __restrict__ e_W, const float* __restrict__ e_b,
    const float* __restrict__ a_W, const float* __restrict__ a_b,
    float* __restrict__ w_ws, float* __restrict__ e_ws, float* __restrict__ a_ws)
{
    __shared__ float smem[2112 + 2 * 32 * EW_LD];  // phaseA: k[16*132]+mkT[128*52]=8768f; phaseB: v[2112]+ew[4256]+aw[4256]=10624f
    __shared__ float lg[16][MKT_LD];
    __shared__ float winv16[16];

    float* k_l  = smem;            // [16][PAD_KV]   (phase A)
    float* mkT  = smem + 2112;     // [128][MKT_LD]  (phase A)
    float* v_l  = smem;            // [16][PAD_KV]   (phase B)
    float* ew_l = smem + 2112;     // [32][EW_LD]    (phase B, per chunk)
    float* aw_l = smem + 2112 + 32 * EW_LD;

    const int tid = threadIdx.x;
    const int p0  = blockIdx.x * 16;

    // ---- phase A stage: k rows (coalesced) + Mk transposed ----
    #pragma unroll
    for (int rep = 0; rep < 2; ++rep) {
        int idx = rep * 256 + tid;          // 0..511 = 16 pos x 32 c4
        int pos = idx >> 5, c4 = idx & 31;
        int qi  = q[p0 + pos];
        *(float4*)&k_l[pos * PAD_KV + c4 * 4] =
            *(const float4*)(k_emb + (size_t)qi * DD + c4 * 4);
    }
    for (int idx = tid; idx < MM * DD; idx += 256) {
        int m = idx >> 7, jj = idx & 127;
        mkT[jj * MKT_LD + m] = Mk[idx];
    }
    __syncthreads();

    // ---- logits: 800 dots; lanes get consecutive m -> conflict-free mkT ----
    for (int j = tid; j < 16 * MM; j += 256) {
        int pos = j / MM, m = j - pos * MM;
        const float* kp = &k_l[pos * PAD_KV];
        float acc = 0.f;
        #pragma unroll 8
        for (int jj = 0; jj < DD; ++jj)
            acc = fmaf(kp[jj], mkT[jj * MKT_LD + m], acc);
        lg[pos][m] = acc;
    }
    __syncthreads();

    // ---- softmax over M=50 ----
    if (tid < 16) {
        float mx = -INFINITY;
        for (int m = 0; m < MM; ++m) mx = fmaxf(mx, lg[tid][m]);
        float sum = 0.f;
        for (int m = 0; m < MM; ++m) {
            float e = expf(lg[tid][m] - mx);
            lg[tid][m] = e;
            sum += e;
        }
        winv16[tid] = 1.f / sum;
    }
    __syncthreads();

    // ---- w out (coalesced) + stage v over old k/mkT region ----
    for (int idx = tid; idx < 16 * MM; idx += 256) {
        int pos = idx / MM, m = idx - pos * MM;
        w_ws[(size_t)(p0 + pos) * MM + m] = lg[pos][m] * winv16[pos];
    }
    #pragma unroll
    for (int rep = 0; rep < 2; ++rep) {
        int idx = rep * 256 + tid;
        int pos = idx >> 5, c4 = idx & 31;
        int gp  = p0 + pos;
        int xi  = q[gp] + NQ * r[gp];
        *(float4*)&v_l[pos * PAD_KV + c4 * 4] =
            *(const float4*)(v_emb + (size_t)xi * DD + c4 * 4);
    }

    // ---- e/a: 4 chunks of 32 output dims; i = tid&31, group g=tid>>5 owns 2 pos ----
    const int i = tid & 31;
    const int g = tid >> 5;          // 8 groups
    const int pos0 = g * 2, pos1 = g * 2 + 1;

    for (int c = 0; c < 4; ++c) {
        __syncthreads();   // prior chunk fully read (and v staged, first iter)
        for (int idx = tid; idx < 32 * 32; idx += 256) {    // 32 rows x 32 float4
            int row = idx >> 5, c4 = idx & 31;
            *(float4*)&ew_l[row * EW_LD + c4 * 4] =
                *(const float4*)(e_W + (size_t)(c * 32 + row) * DD + c4 * 4);
            *(float4*)&aw_l[row * EW_LD + c4 * 4] =
                *(const float4*)(a_W + (size_t)(c * 32 + row) * DD + c4 * 4);
        }
        __syncthreads();

        float ae0 = 0.f, ae1 = 0.f, aa0 = 0.f, aa1 = 0.f;
        for (int j4 = 0; j4 < 32; ++j4) {
            float4 we = *(float4*)&ew_l[i * EW_LD + j4 * 4];
            float4 wa = *(float4*)&aw_l[i * EW_LD + j4 * 4];
            float4 v0 = *(float4*)&v_l[pos0 * PAD_KV + j4 * 4];
            float4 v1 = *(float4*)&v_l[pos1 * PAD_KV + j4 * 4];
            ae0 = dot4(v0, we, ae0);  ae1 = dot4(v1, we, ae1);
            aa0 = dot4(v0, wa, aa0);  aa1 = dot4(v1, wa, aa1);
        }
        const int ig = c * 32 + i;
        const float ebv = e_b[ig], abv = a_b[ig];
        e_ws[(size_t)(p0 + pos0) * DD + ig] = 1.f / (1.f + expf(-(ae0 + ebv)));
        e_ws[(size_t)(p0 + pos1) * DD + ig] = 1.f / (1.f + expf(-(ae1 + ebv)));
        a_ws[(size_t)(p0 + pos0) * DD + ig] = tanhf(aa0 + abv);
        a_ws[(size_t)(p0 + pos1) * DD + ig] = tanhf(aa1 + abv);
    }
}

// ---------------------------------------------------------------------------
// Kernel 2a: per (b, chunk) affine composite S_out = A*S_in + B per (m,d).
// ---------------------------------------------------------------------------
__global__ __launch_bounds__(512) void k_scanA(
    const float* __restrict__ w_ws, const float* __restrict__ e_ws,
    const float* __restrict__ a_ws,
    float* __restrict__ A_ws, float* __restrict__ B_ws)
{
    __shared__ float w_lds[LC * MM];   // 4 KB

    const int b   = blockIdx.x / NC;
    const int c   = blockIdx.x % NC;
    const int tid = threadIdx.x;
    const int d   = tid & 127;
    const int g   = tid >> 7;
    int moff = g * 13; if (g == 3) moff = 38;
    const int mcnt = (g < 2) ? 13 : 12;

    const float* wsrc = w_ws + ((size_t)b * LL + c * LC) * MM;  // contiguous
    for (int idx = tid; idx < LC * MM; idx += 512) w_lds[idx] = wsrc[idx];
    __syncthreads();

    float A[13], Bv[13];
    #pragma unroll
    for (int mi = 0; mi < 13; ++mi) { A[mi] = 1.f; Bv[mi] = 0.f; }

    for (int ll = 0; ll < LC; ++ll) {
        const int gp = b * LL + c * LC + ll;
        const float e = e_ws[(size_t)gp * DD + d];
        const float a = a_ws[(size_t)gp * DD + d];
        const float* wl = w_lds + ll * MM + moff;
        #pragma unroll
        for (int mi = 0; mi < 13; ++mi) {
            if (mi < mcnt) {
                float w_ = wl[mi];
                float cc = fmaf(-w_, e, 1.f);
                A[mi] *= cc;
                Bv[mi] = fmaf(Bv[mi], cc, w_ * a);
            }
        }
    }

    float* Ao = A_ws + ((size_t)b * NC + c) * MM * DD + (size_t)moff * DD + d;
    float* Bo = B_ws + ((size_t)b * NC + c) * MM * DD + (size_t)moff * DD + d;
    #pragma unroll
    for (int mi = 0; mi < 13; ++mi) {
        if (mi < mcnt) { Ao[mi * DD] = A[mi]; Bo[mi * DD] = Bv[mi]; }
    }
}

// ---------------------------------------------------------------------------
// Kernel 2b: sequential composition over chunks; writes chunk ENTRY states
// in-place over A_ws. One thread per (b,m,d).
// ---------------------------------------------------------------------------
__global__ __launch_bounds__(256) void k_scanB(
    const float* __restrict__ Mv0,
    float* __restrict__ A_ws,            // in: A, out: Sentry
    const float* __restrict__ B_ws)
{
    const int g  = blockIdx.x * 256 + threadIdx.x;   // 0 .. B*M*D-1
    const int d  = g & (DD - 1);
    const int md = g >> 7;
    const int m  = md % MM;
    const int b  = md / MM;

    float S = Mv0[m * DD + d];
    const size_t base = ((size_t)b * NC * MM + m) * DD + d;
    #pragma unroll
    for (int c = 0; c < NC; ++c) {
        const size_t off = base + (size_t)c * MM * DD;
        const float Ac = A_ws[off];
        const float Bc = B_ws[off];
        A_ws[off] = S;                     // entry state of chunk c
        S = fmaf(Ac, S, Bc);
    }
}

// ---------------------------------------------------------------------------
// Kernel 2c: replay the scan per (b, chunk) from its entry state; writes all
// Mv states and read[b,l,d] = sum_m w*Mv_pre.
// ---------------------------------------------------------------------------
__global__ __launch_bounds__(512) void k_scanC(
    const float* __restrict__ Sentry,     // == A_ws after k_scanB
    const float* __restrict__ w_ws, const float* __restrict__ e_ws,
    const float* __restrict__ a_ws,
    float* __restrict__ read_ws, float* __restrict__ out_Mv)
{
    __shared__ float w_lds[LC * MM];      // 4 KB
    __shared__ float red[2][4][DD];       // 4 KB

    const int b   = blockIdx.x / NC;
    const int c   = blockIdx.x % NC;
    const int tid = threadIdx.x;
    const int d   = tid & 127;
    const int g   = tid >> 7;
    int moff = g * 13; if (g == 3) moff = 38;
    const int mcnt = (g < 2) ? 13 : 12;

    const float* wsrc = w_ws + ((size_t)b * LL + c * LC) * MM;
    for (int idx = tid; idx < LC * MM; idx += 512) w_lds[idx] = wsrc[idx];

    float S[13];
    const float* Sp = Sentry + ((size_t)b * NC + c) * MM * DD + (size_t)moff * DD + d;
    #pragma unroll
    for (int mi = 0; mi < 13; ++mi)
        if (mi < mcnt) S[mi] = Sp[mi * DD];

    float* outb = out_Mv + (size_t)b * (LL + 1) * MM * DD;
    if (c == 0) {
        #pragma unroll
        for (int mi = 0; mi < 13; ++mi)
            if (mi < mcnt) outb[(moff + mi) * DD + d] = S[mi];  // init state
    }
    __syncthreads();

    for (int ll = 0; ll < LC; ++ll) {
        const int l  = c * LC + ll;
        const int gp = b * LL + l;
        const float e = e_ws[(size_t)gp * DD + d];
        const float a = a_ws[(size_t)gp * DD + d];
        const float* wl = w_lds + ll * MM + moff;

        float racc = 0.f;
        float* o = outb + (size_t)(l + 1) * MM * DD + d;
        #pragma unroll
        for (int mi = 0; mi < 13; ++mi) {
            if (mi < mcnt) {
                float w_ = wl[mi];
                racc = fmaf(w_, S[mi], racc);                // pre-update read
                S[mi] = fmaf(w_, fmaf(-S[mi], e, a), S[mi]); // S += w*(a - S*e)
                o[(moff + mi) * DD] = S[mi];
            }
        }
        red[ll & 1][g][d] = racc;
        __syncthreads();
        if (g == 0)
            read_ws[(size_t)gp * DD + d] =
                red[ll & 1][0][d] + red[ll & 1][1][d] +
                red[ll & 1][2][d] + red[ll & 1][3][d];
    }
}

// ---------------------------------------------------------------------------
// Kernel 3: f = tanh([read,k] @ f_W^T + f_b); p = sigmoid(f . p_W + p_b).
// Block = 16 positions, 256 thr; f_W staged in LDS in 4 chunks of 32 rows.
// Positions partitioned by group -> no cross-wave reduce needed.
// ---------------------------------------------------------------------------
__global__ __launch_bounds__(256) void k_fp(
    const int* __restrict__ q,
    const float* __restrict__ k_emb,
    const float* __restrict__ read_ws,
    const float* __restrict__ f_W, const float* __restrict__ f_b,
    const float* __restrict__ p_W, const float* __restrict__ p_b,
    float* __restrict__ out_p)
{
    __shared__ float cat_l[16][260];          // [read(128) | k(128)] padded
    __shared__ float fw_l[32 * FW_LD];        // one 32-row chunk of f_W

    const int tid = threadIdx.x;
    const int p0  = blockIdx.x * 16;

    #pragma unroll
    for (int rep = 0; rep < 4; ++rep) {
        int idx = rep * 256 + tid;            // 0..1023 = 16 pos x 64 float4
        int pos = idx >> 6, c4 = idx & 63;
        int gp  = p0 + pos;
        float4 val;
        if (c4 < 32) val = *(const float4*)(read_ws + (size_t)gp * DD + c4 * 4);
        else         val = *(const float4*)(k_emb + (size_t)q[gp] * DD + (c4 - 32) * 4);
        *(float4*)&cat_l[pos][c4 * 4] = val;
    }

    const int i = tid & 31;
    const int g = tid >> 5;                  // 8 groups x 2 positions
    const int pos0 = g * 2, pos1 = g * 2 + 1;

    float pp0 = 0.f, pp1 = 0.f;

    for (int c = 0; c < 4; ++c) {
        __syncthreads();   // prior chunk read done (covers cat staging on c=0)
        for (int idx = tid; idx < 32 * 64; idx += 256) {   // 32 rows x 64 float4
            int row = idx >> 6, c4 = idx & 63;
            *(float4*)&fw_l[row * FW_LD + c4 * 4] =
                *(const float4*)(f_W + (size_t)(c * 32 + row) * (2 * DD) + c4 * 4);
        }
        __syncthreads();

        float a0 = 0.f, a1 = 0.f;
        for (int j4 = 0; j4 < 64; ++j4) {
            float4 fw4 = *(float4*)&fw_l[i * FW_LD + j4 * 4];
            float4 c0  = *(float4*)&cat_l[pos0][j4 * 4];
            float4 c1  = *(float4*)&cat_l[pos1][j4 * 4];
            a0 = dot4(c0, fw4, a0);
            a1 = dot4(c1, fw4, a1);
        }
        const int ig = c * 32 + i;
        const float fb = f_b[ig], pw = p_W[ig];
        pp0 = fmaf(tanhf(a0 + fb), pw, pp0);
        pp1 = fmaf(tanhf(a1 + fb), pw, pp1);
    }

    // reduce over the 32 lanes of the group (i dimension)
    #pragma unroll
    for (int mask = 16; mask >= 1; mask >>= 1) {
        pp0 += __shfl_xor(pp0, mask, 64);
        pp1 += __shfl_xor(pp1, mask, 64);
    }
    if (i == 0) {
        out_p[p0 + pos0] = 1.f / (1.f + expf(-(pp0 + p_b[0])));
        out_p[p0 + pos1] = 1.f / (1.f + expf(-(pp1 + p_b[0])));
    }
}

// ---------------------------------------------------------------------------
extern "C" void kernel_launch(void* const* d_in, const int* in_sizes, int n_in,
                              void* d_out, int out_size, void* d_ws, size_t ws_size,
                              hipStream_t stream)
{
    const int*   q     = (const int*)d_in[0];
    const int*   r     = (const int*)d_in[1];
    const float* k_emb = (const float*)d_in[2];
    const float* v_emb = (const float*)d_in[3];
    const float* Mk    = (const float*)d_in[4];
    const float* Mv0   = (const float*)d_in[5];
    const float* f_W   = (const float*)d_in[6];
    const float* f_b   = (const float*)d_in[7];
    const float* p_W   = (const float*)d_in[8];
    const float* p_b   = (const float*)d_in[9];
    const float* e_W   = (const float*)d_in[10];
    const float* e_b   = (const float*)d_in[11];
    const float* a_W   = (const float*)d_in[12];
    const float* a_b   = (const float*)d_in[13];

    float* out_p  = (float*)d_out;           // [B,L]
    float* out_Mv = out_p + NPOS;            // [B,L+1,M,D]

    float* w_ws    = (float*)d_ws;                         // NPOS*MM
    float* e_ws    = w_ws + (size_t)NPOS * MM;             // NPOS*DD
    float* a_ws    = e_ws + (size_t)NPOS * DD;             // NPOS*DD
    float* read_ws = a_ws + (size_t)NPOS * DD;             // NPOS*DD
    float* A_ws    = read_ws + (size_t)NPOS * DD;          // B*NC*MM*DD
    float* B_ws    = A_ws + (size_t)BB * NC * MM * DD;     // B*NC*MM*DD

    hipLaunchKernelGGL(k_wea, dim3(NPOS / 16), dim3(256), 0, stream,
                       q, r, k_emb, v_emb, Mk, e_W, e_b, a_W, a_b,
                       w_ws, e_ws, a_ws);
    hipLaunchKernelGGL(k_scanA, dim3(BB * NC), dim3(512), 0, stream,
                       w_ws, e_ws, a_ws, A_ws, B_ws);
    hipLaunchKernelGGL(k_scanB, dim3((BB * MM * DD) / 256), dim3(256), 0, stream,
                       Mv0, A_ws, B_ws);
    hipLaunchKernelGGL(k_scanC, dim3(BB * NC), dim3(512), 0, stream,
                       A_ws, w_ws, e_ws, a_ws, read_ws, out_Mv);
    hipLaunchKernelGGL(k_fp, dim3(NPOS / 16), dim3(256), 0, stream,
                       q, k_emb, read_ws, f_W, f_b, p_W, p_b, out_p);
}